// Round 17
// baseline (62.943 us; speedup 1.0000x reference)
//
#include <hip/hip_runtime.h>
#include <hip/hip_bf16.h>
#include <hip/hip_fp8.h>

#define B_ROWS 8192
#define E_DIM  1024
#define MARGIN 0.2f
#define BK 64                 // fp8 elements per K-step
#define NSTEPS (E_DIM / BK)   // 16
#define WSCALE 16.0f          // W scaled into e4m3 sweet spot; undone in epilogue

typedef float f32x4 __attribute__((ext_vector_type(4)));

__device__ __forceinline__ void gload_lds16(const void* g, void* l) {
    __builtin_amdgcn_global_load_lds(
        (__attribute__((address_space(1))) void*)(g),
        (__attribute__((address_space(3))) void*)(l),
        16, 0, 0);
}

#define GATE2() do { asm volatile("s_waitcnt vmcnt(2)" ::: "memory"); \
                     __builtin_amdgcn_sched_barrier(0); } while (0)
#define GATE0() do { asm volatile("s_waitcnt vmcnt(0)" ::: "memory"); \
                     __builtin_amdgcn_sched_barrier(0); } while (0)
#define RBAR()  do { __builtin_amdgcn_s_barrier(); \
                     __builtin_amdgcn_sched_barrier(0); } while (0)
#define LGKM0() do { asm volatile("s_waitcnt lgkmcnt(0)" ::: "memory"); \
                     __builtin_amdgcn_sched_barrier(0); } while (0)

__device__ __forceinline__ unsigned char to_fp8(float x) {
    return __hip_fp8_e4m3(x).__x;
}

// blocks [0,4096): c8 = fp8(0.4*m + 0.6*tr_m);
// blocks [4096,5120): Wt8[n][e] = fp8(16 * W[e][n]); blocks [5120,5152): zero delta.
__global__ __launch_bounds__(256)
void prep_combo(const float* __restrict__ m, const float* __restrict__ trm,
                unsigned char* __restrict__ c8,
                const float* __restrict__ W, unsigned char* __restrict__ Wt8,
                float* __restrict__ delta) {
    if (blockIdx.x < 4096) {
        size_t i = ((size_t)blockIdx.x * blockDim.x + threadIdx.x) * 8;
        float4 m0 = *(const float4*)(m + i);
        float4 m1 = *(const float4*)(m + i + 4);
        float4 t0 = *(const float4*)(trm + i);
        float4 t1 = *(const float4*)(trm + i + 4);
        union { unsigned char b[8]; unsigned long long u; } r;
        r.b[0] = to_fp8(0.4f*m0.x + 0.6f*t0.x);
        r.b[1] = to_fp8(0.4f*m0.y + 0.6f*t0.y);
        r.b[2] = to_fp8(0.4f*m0.z + 0.6f*t0.z);
        r.b[3] = to_fp8(0.4f*m0.w + 0.6f*t0.w);
        r.b[4] = to_fp8(0.4f*m1.x + 0.6f*t1.x);
        r.b[5] = to_fp8(0.4f*m1.y + 0.6f*t1.y);
        r.b[6] = to_fp8(0.4f*m1.z + 0.6f*t1.z);
        r.b[7] = to_fp8(0.4f*m1.w + 0.6f*t1.w);
        *(unsigned long long*)(c8 + i) = r.u;
    } else if (blockIdx.x < 5120) {
        __shared__ float tile[32][33];
        const int tb = blockIdx.x - 4096;
        const int bx = (tb & 31) * 32;          // n base
        const int by = (tb >> 5) * 32;          // e base
        const int tx = threadIdx.x & 31;
        const int ty0 = threadIdx.x >> 5;       // 8 rows/thread
#pragma unroll
        for (int r = 0; r < 32; r += 8)
            tile[r + ty0][tx] = W[(size_t)(by + r + ty0) * E_DIM + bx + tx];
        __syncthreads();
#pragma unroll
        for (int r = 0; r < 32; r += 8)
            Wt8[(size_t)(bx + r + ty0) * E_DIM + by + tx] =
                to_fp8(tile[tx][r + ty0] * WSCALE);
    } else {
        delta[(blockIdx.x - 5120) * 256 + threadIdx.x] = 0.f;
    }
}

// TLP experiment, correctness-clean: 64x64 tile, full K, 2048 blocks,
// 24 KiB LDS -> 6 blocks/CU (24 waves/CU, 3x R15 residency). Wave = 32x32
// output via R15-PROVEN mfma_f32_16x16x32_fp8_fp8 (2x2 frags, 8 MFMA/iter).
// Ring-of-3 slots + counted GATE2 + one raw barrier per K-step (R8/R15
// skeleton). Swizzle (row&3)<<4: bits 4-5 ONLY -> exact involution under
// 16B gload_lds staging (the (row&7)<<3 bit-3 swizzle of R15/R16 was
// subtly WRONG: contiguous 16B staging cannot realize an 8B-granule XOR;
// odd rows computed a k-shifted dot). 4-way read conflicts by derivation.
// Epilogue: acc -> f32 u[64][64] in LDS, coalesced float4 dot with
// (Ais - Aem), 16-lane reduce, 64 atomics/block.
__global__ __launch_bounds__(256)
void gemm_dot(const unsigned char* __restrict__ Cm, const unsigned char* __restrict__ Wt,
              const float* __restrict__ Ais, const float* __restrict__ Aem,
              float* __restrict__ delta) {
    __shared__ char smem[24576];   // slot s: A at s*8192, B at s*8192+4096

    const int tid  = threadIdx.x;
    const int lane = tid & 63;
    const int lr   = lane & 15;
    const int hi   = lane >> 4;          // 0..3 : k-subslice
    const int wave = tid >> 6;
    const int wr   = wave >> 1, wc = wave & 1;

    // XCD swizzle: xcd owns 16 row-panels x 16 colb; per-XCD reuse set =
    // 16 c8-panels (1 MiB) + Wt8 (1 MiB) ~ L2-resident.
    const int bid = blockIdx.x;
    const int xcd = bid & 7;
    const int q   = bid >> 3;            // 0..255
    const int rb  = (xcd * 16 + (q >> 4)) * 64;
    const int cb  = (q & 15) * 64;

    auto stage = [&](int slot, int k0) {
        const int d   = tid * 16;                      // 0..4080
        const int row = d >> 6;                        // 64 B per 64-fp8 row
        const int kb  = (d & 63) ^ ((row & 3) << 4);   // bits 4-5 only: exact
        gload_lds16(Cm + (size_t)(rb + row) * E_DIM + k0 + kb,
                    smem + slot * 8192 + d);
        gload_lds16(Wt + (size_t)(cb + row) * E_DIM + k0 + kb,
                    smem + slot * 8192 + 4096 + d);
    };

    f32x4 acc[2][2] = {};

    stage(0, 0);
    stage(1, BK);

    int s0 = 0, s1 = 1, s2 = 2;
    for (int t = 0; t < NSTEPS; ++t) {
        if (t + 1 < NSTEPS) GATE2(); else GATE0();
        RBAR();

        // frag reads: row = (wr|wc)*32 + mi*16 + lr, 8B at (kk*32+hi*8)^swz
        const char* Ab = smem + s0 * 8192;
        const char* Bb = Ab + 4096;
        long a[2][2], b[2][2];
#pragma unroll
        for (int mi = 0; mi < 2; ++mi) {
            const int row = wr * 32 + mi * 16 + lr;
            const int sw  = (row & 3) << 4;
#pragma unroll
            for (int kk = 0; kk < 2; ++kk)
                a[mi][kk] = *(const long*)(Ab + row * 64 + ((kk * 32 + hi * 8) ^ sw));
        }
#pragma unroll
        for (int ni = 0; ni < 2; ++ni) {
            const int row = wc * 32 + ni * 16 + lr;
            const int sw  = (row & 3) << 4;
#pragma unroll
            for (int kk = 0; kk < 2; ++kk)
                b[ni][kk] = *(const long*)(Bb + row * 64 + ((kk * 32 + hi * 8) ^ sw));
        }
        LGKM0();

        if (t + 2 < NSTEPS) stage(s2, (t + 2) * BK);

        __builtin_amdgcn_s_setprio(1);
#pragma unroll
        for (int kk = 0; kk < 2; ++kk)
#pragma unroll
            for (int mi = 0; mi < 2; ++mi)
#pragma unroll
                for (int ni = 0; ni < 2; ++ni)
                    acc[mi][ni] = __builtin_amdgcn_mfma_f32_16x16x32_fp8_fp8(
                        a[mi][kk], b[ni][kk], acc[mi][ni], 0, 0, 0);
        __builtin_amdgcn_s_setprio(0);

        int tmp = s0; s0 = s1; s1 = s2; s2 = tmp;
    }

    // ---- epilogue: u (f32) -> LDS, coalesced dot with (Ais - Aem) ----
    __syncthreads();                      // all waves' LDS reads complete
    float* u = (float*)smem;              // [64][64] f32, 16 KiB

    // 16x16 C/D layout: col = lane&15, row = (lane>>4)*4 + reg
#pragma unroll
    for (int mi = 0; mi < 2; ++mi)
#pragma unroll
        for (int ni = 0; ni < 2; ++ni)
#pragma unroll
            for (int j = 0; j < 4; ++j)
                u[(wr * 32 + mi * 16 + hi * 4 + j) * 64 + wc * 32 + ni * 16 + lr]
                    = acc[mi][ni][j];
    __syncthreads();

    // 16 lanes cover one row's 64 cols (float4 each): fully coalesced
    const int grp = tid >> 4;             // 0..15
    const int lg  = tid & 15;
#pragma unroll
    for (int p = 0; p < 4; ++p) {
        const int rl = p * 16 + grp;
        const size_t g = (size_t)(rb + rl) * E_DIM + cb + lg * 4;
        const float4 ai = *(const float4*)(Ais + g);
        const float4 ae = *(const float4*)(Aem + g);
        const float4 u4 = *(const float4*)(u + rl * 64 + lg * 4);
        float s = u4.x * (ai.x - ae.x)
                + u4.y * (ai.y - ae.y)
                + u4.z * (ai.z - ae.z)
                + u4.w * (ai.w - ae.w);
        s += __shfl_xor(s, 1);
        s += __shfl_xor(s, 2);
        s += __shfl_xor(s, 4);
        s += __shfl_xor(s, 8);
        if (lg == 0) atomicAdd(&delta[rb + rl], s * (1.0f / WSCALE));
    }
}

__global__ void hinge_sum(const float* __restrict__ delta, float* __restrict__ out) {
    float s = 0.f;
    for (int i = threadIdx.x; i < B_ROWS; i += 256)
        s += fmaxf(MARGIN + delta[i], 0.f);
#pragma unroll
    for (int off = 32; off > 0; off >>= 1) s += __shfl_down(s, off);
    __shared__ float wsum[4];
    int lane = threadIdx.x & 63, w = threadIdx.x >> 6;
    if (lane == 0) wsum[w] = s;
    __syncthreads();
    if (threadIdx.x == 0) out[0] = wsum[0] + wsum[1] + wsum[2] + wsum[3];
}

extern "C" void kernel_launch(void* const* d_in, const int* in_sizes, int n_in,
                              void* d_out, int out_size, void* d_ws, size_t ws_size,
                              hipStream_t stream) {
    const float* A_is = (const float*)d_in[0];
    const float* A_em = (const float*)d_in[1];
    const float* m    = (const float*)d_in[2];
    const float* tr_m = (const float*)d_in[3];
    const float* W    = (const float*)d_in[4];
    // d_in[5] = b : cancels in diag_is - diag_em, unused.
    float* out = (float*)d_out;

    char* ws = (char*)d_ws;
    unsigned char* c8  = (unsigned char*)ws;                             // 8 MiB
    unsigned char* wt8 = (unsigned char*)(ws + (size_t)8 * 1024 * 1024); // 1 MiB
    float*         delta = (float*)(ws + (size_t)9 * 1024 * 1024);       // 32 KiB

    prep_combo<<<5152, 256, 0, stream>>>(m, tr_m, c8, W, wt8, delta);
    gemm_dot<<<2048, 256, 0, stream>>>(c8, wt8, A_is, A_em, delta);
    hinge_sum<<<1, 256, 0, stream>>>(delta, out);
}

// Round 18
// 51.266 us; speedup vs baseline: 1.2278x; 1.2278x over previous
//
#include <hip/hip_runtime.h>
#include <hip/hip_bf16.h>
#include <hip/hip_fp8.h>

#define B_ROWS 8192
#define E_DIM  1024
#define MARGIN 0.2f
#define BK 64                 // fp8 elements per K-step (2 ktiles of 32)
#define NSTEPS (E_DIM / BK)   // 16
#define WSCALE 16.0f          // W scaled into e4m3 sweet spot; undone in epilogue

typedef float f32x4 __attribute__((ext_vector_type(4)));

__device__ __forceinline__ void gload_lds16(const void* g, void* l) {
    __builtin_amdgcn_global_load_lds(
        (__attribute__((address_space(1))) void*)(g),
        (__attribute__((address_space(3))) void*)(l),
        16, 0, 0);
}

#define GATE4() do { asm volatile("s_waitcnt vmcnt(4)" ::: "memory"); \
                     __builtin_amdgcn_sched_barrier(0); } while (0)
#define GATE0() do { asm volatile("s_waitcnt vmcnt(0)" ::: "memory"); \
                     __builtin_amdgcn_sched_barrier(0); } while (0)
#define RBAR()  do { __builtin_amdgcn_s_barrier(); \
                     __builtin_amdgcn_sched_barrier(0); } while (0)
#define LGKM0() do { asm volatile("s_waitcnt lgkmcnt(0)" ::: "memory"); \
                     __builtin_amdgcn_sched_barrier(0); } while (0)

__device__ __forceinline__ unsigned char to_fp8(float x) {
    return __hip_fp8_e4m3(x).__x;
}

// Fragment-packed layouts (unit = [panel64][ktile32], 2 KiB each):
//   unit byte (mi*512 + lane*8 + j) = value[row = panel*64 + mi*16 + (lane&15)]
//                                          [k   = ktile*32 + (lane>>4)*8 + j]
// c8p: 128 panels x 32 ktiles (8 MiB). wtp: 16 panels x 32 ktiles (1 MiB),
// value = 16*W[k][n] (transposed on the fly).
// blocks [0,4096): c-pack; [4096,4608): W-pack; [4608,4640): zero delta.
__global__ __launch_bounds__(256)
void prep_combo(const float* __restrict__ m, const float* __restrict__ trm,
                unsigned char* __restrict__ c8p,
                const float* __restrict__ W, unsigned char* __restrict__ wtp,
                float* __restrict__ delta) {
    const int tid = threadIdx.x;
    const int mi  = tid >> 6;
    const int l   = tid & 63;
    const int lr  = l & 15;
    const int hi  = l >> 4;
    if (blockIdx.x < 4096) {
        const int unit  = blockIdx.x;
        const int panel = unit >> 5;
        const int kt    = unit & 31;
        const size_t g  = (size_t)(panel * 64 + mi * 16 + lr) * E_DIM + kt * 32 + hi * 8;
        float4 m0 = *(const float4*)(m + g);
        float4 m1 = *(const float4*)(m + g + 4);
        float4 t0 = *(const float4*)(trm + g);
        float4 t1 = *(const float4*)(trm + g + 4);
        union { unsigned char b[8]; unsigned long long u; } r;
        r.b[0] = to_fp8(0.4f*m0.x + 0.6f*t0.x);
        r.b[1] = to_fp8(0.4f*m0.y + 0.6f*t0.y);
        r.b[2] = to_fp8(0.4f*m0.z + 0.6f*t0.z);
        r.b[3] = to_fp8(0.4f*m0.w + 0.6f*t0.w);
        r.b[4] = to_fp8(0.4f*m1.x + 0.6f*t1.x);
        r.b[5] = to_fp8(0.4f*m1.y + 0.6f*t1.y);
        r.b[6] = to_fp8(0.4f*m1.z + 0.6f*t1.z);
        r.b[7] = to_fp8(0.4f*m1.w + 0.6f*t1.w);
        *(unsigned long long*)(c8p + (size_t)unit * 2048 + mi * 512 + l * 8) = r.u;
    } else if (blockIdx.x < 4608) {
        const int unit = blockIdx.x - 4096;
        const int np   = unit >> 5;
        const int kt   = unit & 31;
        const int n    = np * 64 + mi * 16 + lr;
        const int k0   = kt * 32 + hi * 8;
        union { unsigned char b[8]; unsigned long long u; } r;
#pragma unroll
        for (int j = 0; j < 8; ++j)
            r.b[j] = to_fp8(W[(size_t)(k0 + j) * E_DIM + n] * WSCALE);
        *(unsigned long long*)(wtp + (size_t)unit * 2048 + mi * 512 + l * 8) = r.u;
    } else {
        delta[(blockIdx.x - 4608) * 256 + threadIdx.x] = 0.f;
    }
}

// GEMM on fragment-packed operands: staging is an IDENTITY contiguous copy
// (gload_lds, max coalescing), LDS linear, frag reads = base + lane*8 ->
// 2 lanes/bank = conflict-FREE by construction (m136), zero swizzle.
// R15 skeleton: 128x128 tile, 4 waves (2x2 of 64x64), BK=64, ring-of-3
// slots, counted GATE4 + one raw barrier per K-step. R17-verified math
// (fp8 16x16x32 mapping, WSCALE, epilogue). Epilogue: rowwise dot with
// (Ais - Aem), 16-lane reduce, atomicAdd into delta[].
__global__ __launch_bounds__(256)
void gemm_dot(const unsigned char* __restrict__ c8p, const unsigned char* __restrict__ wtp,
              const float* __restrict__ Ais, const float* __restrict__ Aem,
              float* __restrict__ delta) {
    __shared__ char smem[49152];   // slot s: A at s*16384, B at s*16384+8192

    const int tid  = threadIdx.x;
    const int lane = tid & 63;
    const int lr   = lane & 15;
    const int hi   = lane >> 4;
    const int wave = tid >> 6;
    const int wr   = wave >> 1, wc = wave & 1;

    // XCD swizzle: xcd owns 8 row-panels x 8 colb; per-XCD reuse set =
    // 8 c8-panels (1 MiB) + wtp (1 MiB) ~ L2-resident.
    const int bid = blockIdx.x;
    const int xcd = bid & 7;
    const int q   = bid >> 3;            // 0..63
    const int rb  = (xcd * 8 + (q >> 3)) * 128;
    const int cb  = (q & 7) * 128;
    const int ap0 = rb >> 6;             // first A panel (of 2)
    const int bp0 = cb >> 6;             // first B panel (of 2)

    // stage one K-step (16 KiB: A 4 units + B 4 units), identity copy.
    // unit u = h*2 + kk (h = row-half, kk = ktile within BK).
    auto stage = [&](int slot, int t) {
#pragma unroll
        for (int j = 0; j < 2; ++j) {
            const int off = j * 4096 + tid * 16;   // 0..8191
            const int u   = off >> 11;             // 0..3
            const int w   = off & 2047;
            const size_t gA = ((size_t)(ap0 + (u >> 1)) * 32 + (2 * t + (u & 1))) * 2048 + w;
            const size_t gB = ((size_t)(bp0 + (u >> 1)) * 32 + (2 * t + (u & 1))) * 2048 + w;
            gload_lds16(c8p + gA, smem + slot * 16384 + off);
            gload_lds16(wtp + gB, smem + slot * 16384 + 8192 + off);
        }
    };

    f32x4 acc[4][4] = {};

    stage(0, 0);
    stage(1, 1);

    int s0 = 0, s1 = 1, s2 = 2;
    for (int t = 0; t < NSTEPS; ++t) {
        if (t + 1 < NSTEPS) GATE4(); else GATE0();
        RBAR();

        // frag reads: all lane-linear (base + lane*8), conflict-free
        const char* Ab = smem + s0 * 16384;
        const char* Bb = Ab + 8192;
        long a[4][2], b[4][2];
#pragma unroll
        for (int kk = 0; kk < 2; ++kk) {
            const int au = (wr * 2 + kk) * 2048 + lane * 8;
            const int bu = (wc * 2 + kk) * 2048 + lane * 8;
#pragma unroll
            for (int mi = 0; mi < 4; ++mi) a[mi][kk] = *(const long*)(Ab + au + mi * 512);
#pragma unroll
            for (int ni = 0; ni < 4; ++ni) b[ni][kk] = *(const long*)(Bb + bu + ni * 512);
        }
        LGKM0();

        if (t + 2 < NSTEPS) stage(s2, t + 2);

        __builtin_amdgcn_s_setprio(1);
#pragma unroll
        for (int kk = 0; kk < 2; ++kk)
#pragma unroll
            for (int mi = 0; mi < 4; ++mi)
#pragma unroll
                for (int ni = 0; ni < 4; ++ni)
                    acc[mi][ni] = __builtin_amdgcn_mfma_f32_16x16x32_fp8_fp8(
                        a[mi][kk], b[ni][kk], acc[mi][ni], 0, 0, 0);
        __builtin_amdgcn_s_setprio(0);

        int tmp = s0; s0 = s1; s1 = s2; s2 = tmp;
    }

    // epilogue (R15-measured form): delta[r] += (1/WSCALE) * sum_col u*dA
    // C/D layout (16x16x32): col = lane&15, row = (lane>>4)*4 + reg
    const int colbase = cb + wc * 64 + lr;
    const int rowbase = rb + wr * 64 + hi * 4;
#pragma unroll
    for (int mi = 0; mi < 4; ++mi) {
#pragma unroll
        for (int jj = 0; jj < 4; ++jj) {
            const int r = rowbase + mi * 16 + jj;
            float v = 0.f;
#pragma unroll
            for (int ni = 0; ni < 4; ++ni) {
                const size_t idx = (size_t)r * E_DIM + colbase + ni * 16;
                v += acc[mi][ni][jj] * (Ais[idx] - Aem[idx]);
            }
            v += __shfl_xor(v, 1);
            v += __shfl_xor(v, 2);
            v += __shfl_xor(v, 4);
            v += __shfl_xor(v, 8);
            if (lr == 0) atomicAdd(&delta[r], v * (1.0f / WSCALE));
        }
    }
}

__global__ void hinge_sum(const float* __restrict__ delta, float* __restrict__ out) {
    float s = 0.f;
    for (int i = threadIdx.x; i < B_ROWS; i += 256)
        s += fmaxf(MARGIN + delta[i], 0.f);
#pragma unroll
    for (int off = 32; off > 0; off >>= 1) s += __shfl_down(s, off);
    __shared__ float wsum[4];
    int lane = threadIdx.x & 63, w = threadIdx.x >> 6;
    if (lane == 0) wsum[w] = s;
    __syncthreads();
    if (threadIdx.x == 0) out[0] = wsum[0] + wsum[1] + wsum[2] + wsum[3];
}

extern "C" void kernel_launch(void* const* d_in, const int* in_sizes, int n_in,
                              void* d_out, int out_size, void* d_ws, size_t ws_size,
                              hipStream_t stream) {
    const float* A_is = (const float*)d_in[0];
    const float* A_em = (const float*)d_in[1];
    const float* m    = (const float*)d_in[2];
    const float* tr_m = (const float*)d_in[3];
    const float* W    = (const float*)d_in[4];
    // d_in[5] = b : cancels in diag_is - diag_em, unused.
    float* out = (float*)d_out;

    char* ws = (char*)d_ws;
    unsigned char* c8p = (unsigned char*)ws;                             // 8 MiB
    unsigned char* wtp = (unsigned char*)(ws + (size_t)8 * 1024 * 1024); // 1 MiB
    float*         delta = (float*)(ws + (size_t)9 * 1024 * 1024);       // 32 KiB

    prep_combo<<<4640, 256, 0, stream>>>(m, tr_m, c8p, W, wtp, delta);
    gemm_dot<<<512, 256, 0, stream>>>(c8p, wtp, A_is, A_em, delta);
    hinge_sum<<<1, 256, 0, stream>>>(delta, out);
}

// Round 19
// 51.153 us; speedup vs baseline: 1.2305x; 1.0022x over previous
//
#include <hip/hip_runtime.h>
#include <hip/hip_bf16.h>
#include <hip/hip_fp8.h>

#define B_ROWS 8192
#define E_DIM  1024
#define MARGIN 0.2f
#define BK 128                // fp8 elements per K-step (4 ktiles of 32)
#define NSTEPS (E_DIM / BK)   // 8
#define WSCALE 16.0f          // W scaled into e4m3 sweet spot; undone in epilogue

typedef float f32x4 __attribute__((ext_vector_type(4)));

__device__ __forceinline__ void gload_lds16(const void* g, void* l) {
    __builtin_amdgcn_global_load_lds(
        (__attribute__((address_space(1))) void*)(g),
        (__attribute__((address_space(3))) void*)(l),
        16, 0, 0);
}

#define GATE8() do { asm volatile("s_waitcnt vmcnt(8)" ::: "memory"); \
                     __builtin_amdgcn_sched_barrier(0); } while (0)
#define GATE0() do { asm volatile("s_waitcnt vmcnt(0)" ::: "memory"); \
                     __builtin_amdgcn_sched_barrier(0); } while (0)
#define RBAR()  do { __builtin_amdgcn_s_barrier(); \
                     __builtin_amdgcn_sched_barrier(0); } while (0)
#define LGKM0() do { asm volatile("s_waitcnt lgkmcnt(0)" ::: "memory"); \
                     __builtin_amdgcn_sched_barrier(0); } while (0)

__device__ __forceinline__ unsigned char to_fp8(float x) {
    return __hip_fp8_e4m3(x).__x;
}

// Fragment-packed layouts (unit = [panel64][ktile32], 2 KiB each):
//   unit byte (mi*512 + lane*8 + j) = value[row = panel*64 + mi*16 + (lane&15)]
//                                          [k   = ktile*32 + (lane>>4)*8 + j]
// c8p: 128 panels x 32 ktiles (8 MiB). wtp: 16 panels x 32 ktiles (1 MiB),
// value = 16*W[k][n] (transposed on the fly).
// blocks [0,4096): c-pack; [4096,4608): W-pack; [4608,4640): zero delta.
__global__ __launch_bounds__(256)
void prep_combo(const float* __restrict__ m, const float* __restrict__ trm,
                unsigned char* __restrict__ c8p,
                const float* __restrict__ W, unsigned char* __restrict__ wtp,
                float* __restrict__ delta) {
    const int tid = threadIdx.x;
    const int mi  = tid >> 6;
    const int l   = tid & 63;
    const int lr  = l & 15;
    const int hi  = l >> 4;
    if (blockIdx.x < 4096) {
        const int unit  = blockIdx.x;
        const int panel = unit >> 5;
        const int kt    = unit & 31;
        const size_t g  = (size_t)(panel * 64 + mi * 16 + lr) * E_DIM + kt * 32 + hi * 8;
        float4 m0 = *(const float4*)(m + g);
        float4 m1 = *(const float4*)(m + g + 4);
        float4 t0 = *(const float4*)(trm + g);
        float4 t1 = *(const float4*)(trm + g + 4);
        union { unsigned char b[8]; unsigned long long u; } r;
        r.b[0] = to_fp8(0.4f*m0.x + 0.6f*t0.x);
        r.b[1] = to_fp8(0.4f*m0.y + 0.6f*t0.y);
        r.b[2] = to_fp8(0.4f*m0.z + 0.6f*t0.z);
        r.b[3] = to_fp8(0.4f*m0.w + 0.6f*t0.w);
        r.b[4] = to_fp8(0.4f*m1.x + 0.6f*t1.x);
        r.b[5] = to_fp8(0.4f*m1.y + 0.6f*t1.y);
        r.b[6] = to_fp8(0.4f*m1.z + 0.6f*t1.z);
        r.b[7] = to_fp8(0.4f*m1.w + 0.6f*t1.w);
        *(unsigned long long*)(c8p + (size_t)unit * 2048 + mi * 512 + l * 8) = r.u;
    } else if (blockIdx.x < 4608) {
        const int unit = blockIdx.x - 4096;
        const int np   = unit >> 5;
        const int kt   = unit & 31;
        const int n    = np * 64 + mi * 16 + lr;
        const int k0   = kt * 32 + hi * 8;
        union { unsigned char b[8]; unsigned long long u; } r;
#pragma unroll
        for (int j = 0; j < 8; ++j)
            r.b[j] = to_fp8(W[(size_t)(k0 + j) * E_DIM + n] * WSCALE);
        *(unsigned long long*)(wtp + (size_t)unit * 2048 + mi * 512 + l * 8) = r.u;
    } else {
        delta[(blockIdx.x - 4608) * 256 + threadIdx.x] = 0.f;
    }
}

// FAT-ITERATION GEMM: BK=128 (4 ktiles), NSTEPS=8 -- half the iterations,
// per-iteration overhead (gate+barrier+latency chains) paid half as often.
// Ring-of-2 slots (32 KiB each, 64 KiB total -> 2 blocks/CU). Lifecycle
// (one barrier/iter): GATE8 certifies tile t (newest 8 outstanding = t+1's);
// reads(t); lgkm0; BARRIER (all waves done reading t -> slot t&1 free);
// stage(t+2) into that slot (flight = 2 fat iterations); 64 MFMA.
// Packed operands: staging = identity contiguous copy, frag reads lane-linear
// (conflict-free, R18-verified 0 conflicts). R17-verified fp8 math.
// Epilogue: rowwise dot with (Ais - Aem), 16-lane reduce, atomicAdd.
__global__ __launch_bounds__(256)
void gemm_dot(const unsigned char* __restrict__ c8p, const unsigned char* __restrict__ wtp,
              const float* __restrict__ Ais, const float* __restrict__ Aem,
              float* __restrict__ delta) {
    __shared__ char smem[65536];   // slot s: A at s*32768, B at s*32768+16384

    const int tid  = threadIdx.x;
    const int lane = tid & 63;
    const int lr   = lane & 15;
    const int hi   = lane >> 4;
    const int wave = tid >> 6;
    const int wr   = wave >> 1, wc = wave & 1;

    // XCD swizzle: xcd owns 8 row-panels x 8 colb; per-XCD reuse set =
    // 8 c8-panels (1 MiB) + wtp (1 MiB) ~ L2-resident.
    const int bid = blockIdx.x;
    const int xcd = bid & 7;
    const int q   = bid >> 3;            // 0..63
    const int rb  = (xcd * 8 + (q >> 3)) * 128;
    const int cb  = (q & 7) * 128;
    const int ap0 = rb >> 6;             // first A panel (of 2)
    const int bp0 = cb >> 6;             // first B panel (of 2)

    // stage one K-step (32 KiB: A 8 units + B 8 units), identity copy.
    // unit u = h*4 + kt (h = row-half, kt = ktile 0..3 within BK).
    auto stage = [&](int slot, int t) {
#pragma unroll
        for (int j = 0; j < 4; ++j) {
            const int off = j * 4096 + tid * 16;   // 0..16383
            const int u   = off >> 11;             // 0..7
            const int w   = off & 2047;
            const size_t gA = ((size_t)(ap0 + (u >> 2)) * 32 + (4 * t + (u & 3))) * 2048 + w;
            const size_t gB = ((size_t)(bp0 + (u >> 2)) * 32 + (4 * t + (u & 3))) * 2048 + w;
            gload_lds16(c8p + gA, smem + slot * 32768 + off);
            gload_lds16(wtp + gB, smem + slot * 32768 + 16384 + off);
        }
    };

    f32x4 acc[4][4] = {};

    // prologue: tiles 0,1 (8 loads/thread each; 16 outstanding)
    stage(0, 0);
    stage(1, 1);

    for (int t = 0; t < NSTEPS; ++t) {
        const int s = t & 1;
        if (t + 1 < NSTEPS) GATE8(); else GATE0();   // certify tile t landed

        // frag reads: lane-linear, conflict-free (32 x ds_read_b64)
        const char* Ab = smem + s * 32768;
        const char* Bb = Ab + 16384;
        long a[4][4], b[4][4];
#pragma unroll
        for (int kk = 0; kk < 4; ++kk) {
            const int au = (wr * 4 + kk) * 2048 + lane * 8;
            const int bu = (wc * 4 + kk) * 2048 + lane * 8;
#pragma unroll
            for (int mi = 0; mi < 4; ++mi) a[mi][kk] = *(const long*)(Ab + au + mi * 512);
#pragma unroll
            for (int ni = 0; ni < 4; ++ni) b[ni][kk] = *(const long*)(Bb + bu + ni * 512);
        }
        LGKM0();
        RBAR();    // all waves done reading tile t -> slot s is free

        if (t + 2 < NSTEPS) stage(s, t + 2);   // flight = 2 fat iterations

        __builtin_amdgcn_s_setprio(1);
#pragma unroll
        for (int kk = 0; kk < 4; ++kk)
#pragma unroll
            for (int mi = 0; mi < 4; ++mi)
#pragma unroll
                for (int ni = 0; ni < 4; ++ni)
                    acc[mi][ni] = __builtin_amdgcn_mfma_f32_16x16x32_fp8_fp8(
                        a[mi][kk], b[ni][kk], acc[mi][ni], 0, 0, 0);
        __builtin_amdgcn_s_setprio(0);
    }

    // epilogue (R15/R18-verified): delta[r] += (1/WSCALE) * sum_col u*dA
    // C/D layout (16x16x32): col = lane&15, row = (lane>>4)*4 + reg
    const int colbase = cb + wc * 64 + lr;
    const int rowbase = rb + wr * 64 + hi * 4;
#pragma unroll
    for (int mi = 0; mi < 4; ++mi) {
#pragma unroll
        for (int jj = 0; jj < 4; ++jj) {
            const int r = rowbase + mi * 16 + jj;
            float v = 0.f;
#pragma unroll
            for (int ni = 0; ni < 4; ++ni) {
                const size_t idx = (size_t)r * E_DIM + colbase + ni * 16;
                v += acc[mi][ni][jj] * (Ais[idx] - Aem[idx]);
            }
            v += __shfl_xor(v, 1);
            v += __shfl_xor(v, 2);
            v += __shfl_xor(v, 4);
            v += __shfl_xor(v, 8);
            if (lr == 0) atomicAdd(&delta[r], v * (1.0f / WSCALE));
        }
    }
}

__global__ void hinge_sum(const float* __restrict__ delta, float* __restrict__ out) {
    float s = 0.f;
    for (int i = threadIdx.x; i < B_ROWS; i += 256)
        s += fmaxf(MARGIN + delta[i], 0.f);
#pragma unroll
    for (int off = 32; off > 0; off >>= 1) s += __shfl_down(s, off);
    __shared__ float wsum[4];
    int lane = threadIdx.x & 63, w = threadIdx.x >> 6;
    if (lane == 0) wsum[w] = s;
    __syncthreads();
    if (threadIdx.x == 0) out[0] = wsum[0] + wsum[1] + wsum[2] + wsum[3];
}

extern "C" void kernel_launch(void* const* d_in, const int* in_sizes, int n_in,
                              void* d_out, int out_size, void* d_ws, size_t ws_size,
                              hipStream_t stream) {
    const float* A_is = (const float*)d_in[0];
    const float* A_em = (const float*)d_in[1];
    const float* m    = (const float*)d_in[2];
    const float* tr_m = (const float*)d_in[3];
    const float* W    = (const float*)d_in[4];
    // d_in[5] = b : cancels in diag_is - diag_em, unused.
    float* out = (float*)d_out;

    char* ws = (char*)d_ws;
    unsigned char* c8p = (unsigned char*)ws;                             // 8 MiB
    unsigned char* wtp = (unsigned char*)(ws + (size_t)8 * 1024 * 1024); // 1 MiB
    float*         delta = (float*)(ws + (size_t)9 * 1024 * 1024);       // 32 KiB

    prep_combo<<<4640, 256, 0, stream>>>(m, tr_m, c8p, W, wtp, delta);
    gemm_dot<<<512, 256, 0, stream>>>(c8p, wtp, A_is, A_em, delta);
    hinge_sum<<<1, 256, 0, stream>>>(delta, out);
}